// Round 4
// baseline (2981.260 us; speedup 1.0000x reference)
//
#include <hip/hip_runtime.h>

typedef unsigned short u16;
typedef __attribute__((ext_vector_type(8))) short short8;
typedef __attribute__((ext_vector_type(4))) float f32x4;

#define GLP(p) ((const __attribute__((address_space(1))) void*)(p))
#define LDSP(p) ((__attribute__((address_space(3))) void*)(p))

__device__ inline u16 f2bf(float f) {
  unsigned u = __float_as_uint(f);
  return (u16)((u + 0x7fffu + ((u >> 16) & 1u)) >> 16);
}
__device__ inline float bf2f(u16 h) {
  return __uint_as_float(((unsigned)h) << 16);
}
__device__ inline float tanh_fast(float x) {
  float e = __expf(2.0f * x);
  return 1.0f - 2.0f / (e + 1.0f);
}
__device__ inline unsigned umin_u(unsigned a, unsigned b) { return a < b ? a : b; }

// ---- LLC-direct (coherence point) access: sc0 sc1 bypass L1/L2 --------------
__device__ inline void store_int_sc(int* p, int v) {
  asm volatile("global_store_dword %0, %1, off sc0 sc1" :: "v"(p), "v"(v) : "memory");
}
// issue 8 LLC-direct 16B loads (no wait): d[i] from {plo,phi} + i*1024B
__device__ inline void load8_sc(const u16* plo, const u16* phi,
                                short8& d0, short8& d1, short8& d2, short8& d3,
                                short8& d4, short8& d5, short8& d6, short8& d7) {
  asm volatile(
      "global_load_dwordx4 %0, %8, off sc0 sc1\n\t"
      "global_load_dwordx4 %1, %8, off offset:1024 sc0 sc1\n\t"
      "global_load_dwordx4 %2, %8, off offset:2048 sc0 sc1\n\t"
      "global_load_dwordx4 %3, %8, off offset:3072 sc0 sc1\n\t"
      "global_load_dwordx4 %4, %9, off sc0 sc1\n\t"
      "global_load_dwordx4 %5, %9, off offset:1024 sc0 sc1\n\t"
      "global_load_dwordx4 %6, %9, off offset:2048 sc0 sc1\n\t"
      "global_load_dwordx4 %7, %9, off offset:3072 sc0 sc1\n\t"
      : "=&v"(d0), "=&v"(d1), "=&v"(d2), "=&v"(d3),
        "=&v"(d4), "=&v"(d5), "=&v"(d6), "=&v"(d7)
      : "v"(plo), "v"(phi)
      : "memory");
}
// drain all outstanding vmem; ties the 16 fragment values so uses can't hoist
__device__ inline void wait_all16(short8& a0, short8& a1, short8& a2, short8& a3,
                                  short8& a4, short8& a5, short8& a6, short8& a7,
                                  short8& b0, short8& b1, short8& b2, short8& b3,
                                  short8& b4, short8& b5, short8& b6, short8& b7) {
  asm volatile("s_waitcnt vmcnt(0)"
               : "+v"(a0), "+v"(a1), "+v"(a2), "+v"(a3),
                 "+v"(a4), "+v"(a5), "+v"(a6), "+v"(a7),
                 "+v"(b0), "+v"(b1), "+v"(b2), "+v"(b3),
                 "+v"(b4), "+v"(b5), "+v"(b6), "+v"(b7)
               :: "memory");
}

// ---------------- prep: fp32 -> bf16 conversions -----------------------------
__device__ inline void convseg(const float* __restrict__ s, u16* __restrict__ d,
                               long n4, long t, long S) {
  for (long i = t; i < n4; i += S) {
    float4 v = ((const float4*)s)[i];
    ushort4 o;
    o.x = f2bf(v.x); o.y = f2bf(v.y); o.z = f2bf(v.z); o.w = f2bf(v.w);
    ((ushort4*)d)[i] = o;
  }
}

__global__ __launch_bounds__(256) void prep_kernel(
    const float* __restrict__ x, const float* __restrict__ wih0,
    const float* __restrict__ whh0, const float* __restrict__ wih1,
    const float* __restrict__ whh1,
    u16* __restrict__ xb, u16* __restrict__ wih0b, u16* __restrict__ whh0b,
    u16* __restrict__ wih1b, u16* __restrict__ whh1b) {
  long t = blockIdx.x * 256L + threadIdx.x;
  long S = (long)gridDim.x * 256L;
  convseg(x,    xb,    16777216 / 4, t, S);
  convseg(wih0, wih0b,   524288 / 4, t, S);
  convseg(whh0, whh0b,  1048576 / 4, t, S);
  convseg(wih1, wih1b,  1048576 / 4, t, S);
  convseg(whh1, whh1b,  1048576 / 4, t, S);
}

// zero the 1MB h-ring region (runs AFTER gemm_xproj: the region overlays xb,
// which is dead once the GEMM has consumed it; replay-safe since prep rewrites
// xb fully each launch before gemm reads it).
__global__ __launch_bounds__(256) void zero_kernel(int4* __restrict__ p) {
  int4 z = make_int4(0, 0, 0, 0);
  p[blockIdx.x * 256 + threadIdx.x] = z;
}

// ---------------- GEMM: xp0[m][n] = sum_k x[m][k]*Wih0[n][k] + bih0[n]+bhh0[n]
// M=32768, N=1024, K=512; bf16 in, bf16 out (fp32 accum)
__global__ __launch_bounds__(256, 2) void gemm_xproj(
    const u16* __restrict__ A,   // 32768 x 512
    const u16* __restrict__ Bw,  // 1024 x 512
    const float* __restrict__ bi, const float* __restrict__ bh,
    u16* __restrict__ C) {       // 32768 x 1024
  __shared__ u16 As[128 * 64];
  __shared__ u16 Bs[128 * 64];
  const int tid = threadIdx.x;
  const int lane = tid & 63;
  const int w = tid >> 6;
  const int ln = lane & 15, kg = lane >> 4;
  const int m0 = blockIdx.x * 128;
  const int n0 = blockIdx.y * 128;
  const int mi = (w & 1) * 64, ni = (w >> 1) * 64;

  f32x4 acc[4][4] = {};
  float bias[4];
#pragma unroll
  for (int nj = 0; nj < 4; ++nj) bias[nj] = bi[n0 + ni + nj * 16 + ln] + bh[n0 + ni + nj * 16 + ln];

  const int lrow = lane >> 3;
  const int lcol = (lane & 7) * 8;

  for (int kt = 0; kt < 512; kt += 64) {
#pragma unroll
    for (int i = 0; i < 4; ++i) {
      int row = i * 32 + w * 8;
      const u16* ga = A + (long)(m0 + row + lrow) * 512 + kt + lcol;
      __builtin_amdgcn_global_load_lds(GLP(ga), LDSP(As + row * 64), 16, 0, 0);
      const u16* gb = Bw + (long)(n0 + row + lrow) * 512 + kt + lcol;
      __builtin_amdgcn_global_load_lds(GLP(gb), LDSP(Bs + row * 64), 16, 0, 0);
    }
    __syncthreads();
#pragma unroll
    for (int kc = 0; kc < 64; kc += 32) {
      short8 af[4], bf[4];
#pragma unroll
      for (int i = 0; i < 4; ++i) {
        af[i] = *(const short8*)(As + (mi + i * 16 + ln) * 64 + kc + kg * 8);
        bf[i] = *(const short8*)(Bs + (ni + i * 16 + ln) * 64 + kc + kg * 8);
      }
#pragma unroll
      for (int a = 0; a < 4; ++a)
#pragma unroll
        for (int b = 0; b < 4; ++b)
          acc[a][b] = __builtin_amdgcn_mfma_f32_16x16x32_bf16(af[a], bf[b], acc[a][b], 0, 0, 0);
    }
    __syncthreads();
  }
#pragma unroll
  for (int a = 0; a < 4; ++a)
#pragma unroll
    for (int b = 0; b < 4; ++b)
#pragma unroll
      for (int r = 0; r < 4; ++r) {
        int m = m0 + mi + a * 16 + kg * 4 + r;
        int n = n0 + ni + b * 16 + ln;
        C[(long)m * 1024 + n] = f2bf(acc[a][b][r] + bias[b]);
      }
}

// ---------------- persistent pipelined 2-layer recurrence --------------------
// FLAGLESS SENTINEL PROTOCOL. 256 blocks x 256 threads; block = (q 0..3) x
// (c 0..63). h bufs: 4-slot ring per layer (slot = step&3), tile-blocked as the
// verified baseline (tile c = contiguous 512B [16 m][16 j], exclusive owner).
// Producer stores DWORD pairs (lane-pairing via shfl_xor -> 4B-atomic stores)
// with +0 -> -0 substitution, so 0x0000 never occurs in live data. Consumer
// polls by loading its actual fragments and accepting when every dword != 0
// (dword atomicity => nonzero <=> final value). No store-ack, no flag, no
// discovery RT: handshake = store flight + one poll-load RT.
// Ring recycling: at epilogue(it) each producer re-zeroes its own tile in
// h1 slot (it+2)&3 / h2 slot (it+1)&3. Safe: any block at iteration it =>
// all blocks completed the loads of iteration it-2 (they had to, to produce
// h[it-1], which this block consumed), so nobody still reads - or can falsely
// accept - the zeroed generation. Spin budget converts any protocol violation
// into a bounded wrong answer instead of a hang.
__global__ __launch_bounds__(256, 1) void rnn_persist(
    const u16* __restrict__ whh0, const u16* __restrict__ wih1,
    const u16* __restrict__ whh1, const u16* __restrict__ xp0,
    const float* __restrict__ bih1, const float* __restrict__ bhh1,
    u16* __restrict__ h1buf, u16* __restrict__ h2buf) {
  const int tid = threadIdx.x;
  const int lane = tid & 63;
  const int w = tid >> 6;
  const int ln = lane & 15, kg = lane >> 4;
  const int q = blockIdx.x >> 6;
  const int c = blockIdx.x & 63;
  const int m0 = q * 16;
  const int j0 = c * 16;
  const int kb = w * 256;  // this wave's K-chunk base (K split 4 ways)

  // persistent weight fragments (B-operand layout: n=lane&15 -> row j0+ln)
  short8 WA[8], W1[8], W2[8];
#pragma unroll
  for (int i = 0; i < 8; ++i) {
    int off = (j0 + ln) * 1024 + kb + i * 32 + kg * 8;
    WA[i] = *(const short8*)(whh0 + off);
    W1[i] = *(const short8*)(wih1 + off);
    W2[i] = *(const short8*)(whh1 + off);
  }
  const float bias1 = bih1[j0 + ln] + bhh1[j0 + ln];

  __shared__ float red[2][2][4][256];  // [it parity][layer][wave][lane*4]

  // consumer A-fragment base (tiled layout), per wave/lane:
  // elem = (w*16 + (kg>>1) + i*2)*256 + ln*16 + (kg&1)*8, i advances by 512
  const int lbase = (w * 16 + (kg >> 1)) * 256 + ln * 16 + (kg & 1) * 8;
  const u16* hq1 = h1buf + q * 16384 + lbase;  // + slot*65536
  const u16* hq2 = h2buf + q * 16384 + lbase;

  short8 H1[8], H2[8];
  u16 xpv[4];

  // ---- initial state: h1[-1] = 0, h2[-2] = 0 -> plain zero registers -------
  short8 zz = {0, 0, 0, 0, 0, 0, 0, 0};
#pragma unroll
  for (int i = 0; i < 8; ++i) { H1[i] = zz; H2[i] = zz; }
  if (w == 0) {
#pragma unroll
    for (int r = 0; r < 4; ++r)
      xpv[r] = xp0[((long)(m0 + kg * 4 + r) * 512 + 0) * 1024 + j0 + ln];
  }

  for (int it = 0; it <= 512; ++it) {
    const int rp = it & 1;
    f32x4 accA = {}, accB = {};
#pragma unroll
    for (int i = 0; i < 8; ++i) accA = __builtin_amdgcn_mfma_f32_16x16x32_bf16(H1[i], WA[i], accA, 0, 0, 0);
#pragma unroll
    for (int i = 0; i < 8; ++i) accB = __builtin_amdgcn_mfma_f32_16x16x32_bf16(H1[i], W1[i], accB, 0, 0, 0);
#pragma unroll
    for (int i = 0; i < 8; ++i) accB = __builtin_amdgcn_mfma_f32_16x16x32_bf16(H2[i], W2[i], accB, 0, 0, 0);
    *(f32x4*)&red[rp][0][w][lane * 4] = accA;
    *(f32x4*)&red[rp][1][w][lane * 4] = accB;
    __syncthreads();  // the ONLY workgroup barrier this iteration

    if (w == 0) {
      if (it < 512) {  // epilogue layer 0 -> h1[it], slot it&3
        f32x4 s = *(const f32x4*)&red[rp][0][0][lane * 4];
        s += *(const f32x4*)&red[rp][0][1][lane * 4];
        s += *(const f32x4*)&red[rp][0][2][lane * 4];
        s += *(const f32x4*)&red[rp][0][3][lane * 4];
        u16* h1w = h1buf + (it & 3) * 65536 + q * 16384 + c * 256;
        u16* h1z = h1buf + ((it + 2) & 3) * 65536 + q * 16384 + c * 256;
#pragma unroll
        for (int r = 0; r < 4; ++r) {
          float z = s[r] + bf2f(xpv[r]);  // D layout: row=kg*4+r, col=ln
          unsigned hv = (unsigned)f2bf(tanh_fast(z));
          if (hv == 0u) hv = 0x8000u;  // -0.0: numerically identical, nonzero bits
          unsigned pv = ((unsigned)__shfl_xor((int)hv, 1, 64)) & 0xFFFFu;
          if ((ln & 1) == 0) {  // even lane stores the (ln, ln+1) dword pair
            const int idx = (kg * 4 + r) * 16 + ln;
            store_int_sc((int*)(h1w + idx), (int)(hv | (pv << 16)));
            store_int_sc((int*)(h1z + idx), 0);  // recycle old generation
          }
        }
      }
    } else if (w == 1) {
      if (it >= 1) {  // epilogue layer 1 -> h2[it-1], slot (it-1)&3
        f32x4 s = *(const f32x4*)&red[rp][1][0][lane * 4];
        s += *(const f32x4*)&red[rp][1][1][lane * 4];
        s += *(const f32x4*)&red[rp][1][2][lane * 4];
        s += *(const f32x4*)&red[rp][1][3][lane * 4];
        u16* h2w = h2buf + ((it - 1) & 3) * 65536 + q * 16384 + c * 256;
        u16* h2z = h2buf + ((it + 1) & 3) * 65536 + q * 16384 + c * 256;
#pragma unroll
        for (int r = 0; r < 4; ++r) {
          float z = s[r] + bias1;
          unsigned hv = (unsigned)f2bf(tanh_fast(z));
          if (hv == 0u) hv = 0x8000u;
          unsigned pv = ((unsigned)__shfl_xor((int)hv, 1, 64)) & 0xFFFFu;
          if ((ln & 1) == 0) {
            const int idx = (kg * 4 + r) * 16 + ln;
            store_int_sc((int*)(h2w + idx), (int)(hv | (pv << 16)));
            store_int_sc((int*)(h2z + idx), 0);
          }
        }
      }
    }

    if (it < 512) {
      // sentinel poll: load the actual fragments, accept when all dwords != 0
      const u16* p1 = hq1 + (it & 3) * 65536;
      const u16* p2 = hq2 + ((it - 1) & 3) * 65536;  // h2[it-1]; unused at it=0
      int bud = 1 << 20;
      while (true) {
        load8_sc(p1, p1 + 2048, H1[0], H1[1], H1[2], H1[3], H1[4], H1[5], H1[6], H1[7]);
        if (it > 0)
          load8_sc(p2, p2 + 2048, H2[0], H2[1], H2[2], H2[3], H2[4], H2[5], H2[6], H2[7]);
        wait_all16(H1[0], H1[1], H1[2], H1[3], H1[4], H1[5], H1[6], H1[7],
                   H2[0], H2[1], H2[2], H2[3], H2[4], H2[5], H2[6], H2[7]);
        unsigned ma = 0xFFFFFFFFu, mb = 0xFFFFFFFFu, mc = 0xFFFFFFFFu, md = 0xFFFFFFFFu;
#pragma unroll
        for (int i = 0; i < 8; ++i) {
          unsigned u[4];
          __builtin_memcpy(u, &H1[i], 16);
          ma = umin_u(ma, u[0]); mb = umin_u(mb, u[1]);
          mc = umin_u(mc, u[2]); md = umin_u(md, u[3]);
        }
        if (it > 0) {
#pragma unroll
          for (int i = 0; i < 8; ++i) {
            unsigned u[4];
            __builtin_memcpy(u, &H2[i], 16);
            ma = umin_u(ma, u[0]); mb = umin_u(mb, u[1]);
            mc = umin_u(mc, u[2]); md = umin_u(md, u[3]);
          }
        }
        unsigned mm = umin_u(umin_u(ma, mb), umin_u(mc, md));
        if (mm != 0u || --bud == 0) break;  // per-lane exit; budget kills hangs
      }
      // xp0 prefetch for it+1: issued AFTER the poll (a vmcnt(0) fence) so its
      // HBM latency hides under MFMA+barrier, not under the poll's first probe
      // (round-3 lesson). Compiler inserts the waitcnt before the epilogue use.
      if (w == 0 && it < 511) {
#pragma unroll
        for (int r = 0; r < 4; ++r)
          xpv[r] = xp0[((long)(m0 + kg * 4 + r) * 512 + (it + 1)) * 1024 + j0 + ln];
      }
    }
  }
}

// ---------------- FC head: out[b] = sigmoid(h2[511][b,:] . fc_w + fc_b) ------
// h2[511] lives in ring slot 511&3 = 3 (tiled layout).
__global__ __launch_bounds__(256) void fc_kernel(const u16* __restrict__ h2,
                                                 const float* __restrict__ fcw,
                                                 const float* __restrict__ fcb,
                                                 float* __restrict__ out) {
  const int lane = threadIdx.x & 63;
  const int w = threadIdx.x >> 6;
  float wreg[16];
#pragma unroll
  for (int i = 0; i < 16; ++i) wreg[i] = fcw[lane * 16 + i];
  for (int b = w; b < 64; b += 4) {
    const int q = b >> 4, mb = b & 15;
    const u16* hp = h2 + 3 * 65536 + q * 16384 + lane * 256 + mb * 16;  // slot 3
    float s = 0.f;
#pragma unroll
    for (int i = 0; i < 16; ++i) s += bf2f(hp[i]) * wreg[i];
#pragma unroll
    for (int off = 32; off > 0; off >>= 1) s += __shfl_down(s, off, 64);
    if (lane == 0) out[b] = 1.0f / (1.0f + __expf(-(s + fcb[0])));
  }
}

extern "C" void kernel_launch(void* const* d_in, const int* in_sizes, int n_in,
                              void* d_out, int out_size, void* d_ws, size_t ws_size,
                              hipStream_t stream) {
  const float* x    = (const float*)d_in[0];
  const float* wih0 = (const float*)d_in[1];
  const float* whh0 = (const float*)d_in[2];
  const float* bih0 = (const float*)d_in[3];
  const float* bhh0 = (const float*)d_in[4];
  const float* wih1 = (const float*)d_in[5];
  const float* whh1 = (const float*)d_in[6];
  const float* bih1 = (const float*)d_in[7];
  const float* bhh1 = (const float*)d_in[8];
  const float* fcw  = (const float*)d_in[9];
  const float* fcb  = (const float*)d_in[10];

  char* ws = (char*)d_ws;
  u16* xb    = (u16*)(ws);                  // 33,554,432 B (dead after gemm)
  u16* h1buf = (u16*)(ws);                  //    524,288 B (4 slots) overlays xb
  u16* h2buf = (u16*)(ws + 524288);         //    524,288 B (4 slots) overlays xb
  u16* wih0b = (u16*)(ws + 33554432);       //  1,048,576 B
  u16* whh0b = (u16*)(ws + 34603008);       //  2,097,152 B
  u16* wih1b = (u16*)(ws + 36700160);       //  2,097,152 B
  u16* whh1b = (u16*)(ws + 38797312);       //  2,097,152 B
  u16* xp0   = (u16*)(ws + 40894464);       // 67,108,864 B

  prep_kernel<<<1024, 256, 0, stream>>>(x, wih0, whh0, wih1, whh1, xb, wih0b,
                                        whh0b, wih1b, whh1b);
  dim3 gg(256, 8);
  gemm_xproj<<<gg, 256, 0, stream>>>(xb, wih0b, bih0, bhh0, xp0);
  zero_kernel<<<256, 256, 0, stream>>>((int4*)ws);  // init h rings (1MB)
  rnn_persist<<<256, 256, 0, stream>>>(whh0b, wih1b, whh1b, xp0, bih1, bhh1,
                                       h1buf, h2buf);
  fc_kernel<<<1, 256, 0, stream>>>(h2buf, fcw, fcb, (float*)d_out);
}

// Round 5
// 2928.597 us; speedup vs baseline: 1.0180x; 1.0180x over previous
//
#include <hip/hip_runtime.h>

typedef unsigned short u16;
typedef __attribute__((ext_vector_type(8))) short short8;
typedef __attribute__((ext_vector_type(4))) float f32x4;

#define GLP(p) ((const __attribute__((address_space(1))) void*)(p))
#define LDSP(p) ((__attribute__((address_space(3))) void*)(p))

__device__ inline u16 f2bf(float f) {
  unsigned u = __float_as_uint(f);
  return (u16)((u + 0x7fffu + ((u >> 16) & 1u)) >> 16);
}
__device__ inline float bf2f(u16 h) {
  return __uint_as_float(((unsigned)h) << 16);
}
__device__ inline float tanh_fast(float x) {
  float e = __expf(2.0f * x);
  return 1.0f - 2.0f / (e + 1.0f);
}

// ---- LLC-direct (coherence point) access helpers: sc0 sc1 bypass L1/L2 ------
__device__ inline void store_short_sc(u16* p, unsigned v) {
  asm volatile("global_store_short %0, %1, off sc0 sc1" :: "v"(p), "v"(v) : "memory");
}
__device__ inline int load_int_sc(const int* p) {
  int v;
  asm volatile("global_load_dword %0, %1, off sc0 sc1\n\t"
               "s_waitcnt vmcnt(0)"
               : "=&v"(v) : "v"(p) : "memory");
  return v;
}
// issue 8 LLC-direct 16B loads (no wait): d[i] from {plo,phi} + i*1024B
__device__ inline void load8_sc(const u16* plo, const u16* phi,
                                short8& d0, short8& d1, short8& d2, short8& d3,
                                short8& d4, short8& d5, short8& d6, short8& d7) {
  asm volatile(
      "global_load_dwordx4 %0, %8, off sc0 sc1\n\t"
      "global_load_dwordx4 %1, %8, off offset:1024 sc0 sc1\n\t"
      "global_load_dwordx4 %2, %8, off offset:2048 sc0 sc1\n\t"
      "global_load_dwordx4 %3, %8, off offset:3072 sc0 sc1\n\t"
      "global_load_dwordx4 %4, %9, off sc0 sc1\n\t"
      "global_load_dwordx4 %5, %9, off offset:1024 sc0 sc1\n\t"
      "global_load_dwordx4 %6, %9, off offset:2048 sc0 sc1\n\t"
      "global_load_dwordx4 %7, %9, off offset:3072 sc0 sc1\n\t"
      : "=&v"(d0), "=&v"(d1), "=&v"(d2), "=&v"(d3),
        "=&v"(d4), "=&v"(d5), "=&v"(d6), "=&v"(d7)
      : "v"(plo), "v"(phi)
      : "memory");
}
// drain all outstanding vmem; ties the 16 fragment values so MFMAs can't hoist
__device__ inline void wait_all16(short8& a0, short8& a1, short8& a2, short8& a3,
                                  short8& a4, short8& a5, short8& a6, short8& a7,
                                  short8& b0, short8& b1, short8& b2, short8& b3,
                                  short8& b4, short8& b5, short8& b6, short8& b7) {
  asm volatile("s_waitcnt vmcnt(0)"
               : "+v"(a0), "+v"(a1), "+v"(a2), "+v"(a3),
                 "+v"(a4), "+v"(a5), "+v"(a6), "+v"(a7),
                 "+v"(b0), "+v"(b1), "+v"(b2), "+v"(b3),
                 "+v"(b4), "+v"(b5), "+v"(b6), "+v"(b7)
               :: "memory");
}
// poll one of 4 monotonic sub-counters (lane&3) until >= target. Uniform
// address within each lane-quad -> 4 LLC requests per probe (vs round-0's 64
// gathered 128B-strided lines). Wave exits only when all lanes pass, i.e. all
// 64 producers of the group have published. Semantics identical to round-0.
__device__ inline void poll_cnt(const int* p, int target) {
  while (load_int_sc(p) < target) {}
}

// ---------------- prep: fp32 -> bf16 conversions, zero h buffers & flags -----
__device__ inline void convseg(const float* __restrict__ s, u16* __restrict__ d,
                               long n4, long t, long S) {
  for (long i = t; i < n4; i += S) {
    float4 v = ((const float4*)s)[i];
    ushort4 o;
    o.x = f2bf(v.x); o.y = f2bf(v.y); o.z = f2bf(v.z); o.w = f2bf(v.w);
    ((ushort4*)d)[i] = o;
  }
}

__global__ __launch_bounds__(256) void prep_kernel(
    const float* __restrict__ x, const float* __restrict__ wih0,
    const float* __restrict__ whh0, const float* __restrict__ wih1,
    const float* __restrict__ whh1,
    u16* __restrict__ xb, u16* __restrict__ wih0b, u16* __restrict__ whh0b,
    u16* __restrict__ wih1b, u16* __restrict__ whh1b,
    u16* __restrict__ hbufs, int* __restrict__ bar) {
  long t = blockIdx.x * 256L + threadIdx.x;
  long S = (long)gridDim.x * 256L;
  convseg(x,    xb,    16777216 / 4, t, S);
  convseg(wih0, wih0b,   524288 / 4, t, S);
  convseg(whh0, whh0b,  1048576 / 4, t, S);
  convseg(wih1, wih1b,  1048576 / 4, t, S);
  convseg(whh1, whh1b,  1048576 / 4, t, S);
  // zero h1(2 parities) + h2(2 parities): 524288 B = 65536 ushort4
  ushort4 z4 = make_ushort4(0, 0, 0, 0);
  for (long i = t; i < 65536; i += S) ((ushort4*)hbufs)[i] = z4;
  // zero counter region: 16384 ints = 4096 int4
  int4 zi = make_int4(0, 0, 0, 0);
  for (long i = t; i < 4096; i += S) ((int4*)bar)[i] = zi;
}

// ---------------- GEMM: xp0[m][n] = sum_k x[m][k]*Wih0[n][k] + bih0[n]+bhh0[n]
// M=32768, N=1024, K=512; bf16 in, bf16 out (fp32 accum)
__global__ __launch_bounds__(256, 2) void gemm_xproj(
    const u16* __restrict__ A,   // 32768 x 512
    const u16* __restrict__ Bw,  // 1024 x 512
    const float* __restrict__ bi, const float* __restrict__ bh,
    u16* __restrict__ C) {       // 32768 x 1024
  __shared__ u16 As[128 * 64];
  __shared__ u16 Bs[128 * 64];
  const int tid = threadIdx.x;
  const int lane = tid & 63;
  const int w = tid >> 6;
  const int ln = lane & 15, kg = lane >> 4;
  const int m0 = blockIdx.x * 128;
  const int n0 = blockIdx.y * 128;
  const int mi = (w & 1) * 64, ni = (w >> 1) * 64;

  f32x4 acc[4][4] = {};
  float bias[4];
#pragma unroll
  for (int nj = 0; nj < 4; ++nj) bias[nj] = bi[n0 + ni + nj * 16 + ln] + bh[n0 + ni + nj * 16 + ln];

  const int lrow = lane >> 3;
  const int lcol = (lane & 7) * 8;

  for (int kt = 0; kt < 512; kt += 64) {
#pragma unroll
    for (int i = 0; i < 4; ++i) {
      int row = i * 32 + w * 8;
      const u16* ga = A + (long)(m0 + row + lrow) * 512 + kt + lcol;
      __builtin_amdgcn_global_load_lds(GLP(ga), LDSP(As + row * 64), 16, 0, 0);
      const u16* gb = Bw + (long)(n0 + row + lrow) * 512 + kt + lcol;
      __builtin_amdgcn_global_load_lds(GLP(gb), LDSP(Bs + row * 64), 16, 0, 0);
    }
    __syncthreads();
#pragma unroll
    for (int kc = 0; kc < 64; kc += 32) {
      short8 af[4], bf[4];
#pragma unroll
      for (int i = 0; i < 4; ++i) {
        af[i] = *(const short8*)(As + (mi + i * 16 + ln) * 64 + kc + kg * 8);
        bf[i] = *(const short8*)(Bs + (ni + i * 16 + ln) * 64 + kc + kg * 8);
      }
#pragma unroll
      for (int a = 0; a < 4; ++a)
#pragma unroll
        for (int b = 0; b < 4; ++b)
          acc[a][b] = __builtin_amdgcn_mfma_f32_16x16x32_bf16(af[a], bf[b], acc[a][b], 0, 0, 0);
    }
    __syncthreads();
  }
#pragma unroll
  for (int a = 0; a < 4; ++a)
#pragma unroll
    for (int b = 0; b < 4; ++b)
#pragma unroll
      for (int r = 0; r < 4; ++r) {
        int m = m0 + mi + a * 16 + kg * 4 + r;
        int n = n0 + ni + b * 16 + ln;
        C[(long)m * 1024 + n] = f2bf(acc[a][b][r] + bias[b]);
      }
}

// ---------------- persistent pipelined 2-layer recurrence --------------------
// 256 blocks x 256 threads; block = (q in 0..3) x (c in 0..63); group = 64
// blocks sharing q (batch rows q*16..+16). h bufs are TILE-BLOCKED: per parity
// per q, tile c is a contiguous 512B [16 mb][16 jj] region owned exclusively
// by producer block (q,c). One __syncthreads per iteration (LDS red
// double-buffered). Identical to the verified round-0 kernel EXCEPT the
// handshake medium: per-producer 128B flag lines are replaced by 4 monotonic
// sub-counters per (q,layer) (1KB apart -> distinct LLC slices; 16 producers
// each). Producer publishes with a system-scope atomic +1 issued after the
// data-store vmcnt(0) ack (same ordering guarantee as the old flag store);
// consumer polls counter >= 16*(it+1). This cuts per-probe LLC requests from
// 64 gathered lines to 4 uniform ones (16x less poll traffic, same sampling
// rate, same semantics) - attacking the LLC congestion that inflates every
// round trip on the serial chain.
__global__ __launch_bounds__(256, 1) void rnn_persist(
    const u16* __restrict__ whh0, const u16* __restrict__ wih1,
    const u16* __restrict__ whh1, const u16* __restrict__ xp0,
    const float* __restrict__ bih1, const float* __restrict__ bhh1,
    u16* __restrict__ h1buf, u16* __restrict__ h2buf, int* __restrict__ bar) {
  const int tid = threadIdx.x;
  const int lane = tid & 63;
  const int w = tid >> 6;
  const int ln = lane & 15, kg = lane >> 4;
  const int q = blockIdx.x >> 6;
  const int c = blockIdx.x & 63;
  const int m0 = q * 16;
  const int j0 = c * 16;
  const int kb = w * 256;  // this wave's K-chunk base (K split 4 ways)

  // persistent weight fragments (B-operand layout: n=lane&15 -> row j0+ln)
  short8 WA[8], W1[8], W2[8];
#pragma unroll
  for (int i = 0; i < 8; ++i) {
    int off = (j0 + ln) * 1024 + kb + i * 32 + kg * 8;
    WA[i] = *(const short8*)(whh0 + off);
    W1[i] = *(const short8*)(wih1 + off);
    W2[i] = *(const short8*)(whh1 + off);
  }
  const float bias1 = bih1[j0 + ln] + bhh1[j0 + ln];

  __shared__ float red[2][2][4][256];  // [it parity][layer][wave][lane*4]
  // counters (ints): cntA[q][s] at q*1024 + s*256; cntB at +4096
  int* cntA = bar + q * 1024;
  int* cntB = bar + 4096 + q * 1024;
  int* myA = cntA + (c >> 4) * 256;          // this producer's sub-counter
  int* myB = cntB + (c >> 4) * 256;
  const int* pA = cntA + (lane & 3) * 256;   // lane polls sub-counter lane&3
  const int* pB = cntB + (lane & 3) * 256;

  // consumer A-fragment base (tiled layout), per wave/lane:
  // elem = (w*16 + (kg>>1) + i*2)*256 + ln*16 + (kg&1)*8, i advances by 512
  const int lbase = (w * 16 + (kg >> 1)) * 256 + ln * 16 + (kg & 1) * 8;
  const u16* hq1 = h1buf + q * 16384 + lbase;  // + parity*65536
  const u16* hq2 = h2buf + q * 16384 + lbase;

  short8 H1[8], H2[8];
  u16 xpv[4];

  // ---- pre-loop loads for it=0: h1[-1] parity 1, h2[-2] parity 0 (zeroed) --
  {
    const u16* p1 = hq1 + 65536;
    const u16* p2 = hq2;
    load8_sc(p1, p1 + 2048, H1[0], H1[1], H1[2], H1[3], H1[4], H1[5], H1[6], H1[7]);
    load8_sc(p2, p2 + 2048, H2[0], H2[1], H2[2], H2[3], H2[4], H2[5], H2[6], H2[7]);
    if (w == 0) {
#pragma unroll
      for (int r = 0; r < 4; ++r)
        xpv[r] = xp0[((long)(m0 + kg * 4 + r) * 512 + 0) * 1024 + j0 + ln];
    }
    wait_all16(H1[0], H1[1], H1[2], H1[3], H1[4], H1[5], H1[6], H1[7],
               H2[0], H2[1], H2[2], H2[3], H2[4], H2[5], H2[6], H2[7]);
  }

  for (int it = 0; it <= 512; ++it) {
    const int rp = it & 1;
    f32x4 accA = {}, accB = {};
#pragma unroll
    for (int i = 0; i < 8; ++i) accA = __builtin_amdgcn_mfma_f32_16x16x32_bf16(H1[i], WA[i], accA, 0, 0, 0);
#pragma unroll
    for (int i = 0; i < 8; ++i) accB = __builtin_amdgcn_mfma_f32_16x16x32_bf16(H1[i], W1[i], accB, 0, 0, 0);
#pragma unroll
    for (int i = 0; i < 8; ++i) accB = __builtin_amdgcn_mfma_f32_16x16x32_bf16(H2[i], W2[i], accB, 0, 0, 0);
    *(f32x4*)&red[rp][0][w][lane * 4] = accA;
    *(f32x4*)&red[rp][1][w][lane * 4] = accB;
    __syncthreads();  // the ONLY workgroup barrier this iteration

    if (w == 0) {
      if (it < 512) {  // epilogue layer 0 -> h1[it] (tile-blocked, exclusive)
        f32x4 s = *(const f32x4*)&red[rp][0][0][lane * 4];
        s += *(const f32x4*)&red[rp][0][1][lane * 4];
        s += *(const f32x4*)&red[rp][0][2][lane * 4];
        s += *(const f32x4*)&red[rp][0][3][lane * 4];
        u16* h1w = h1buf + (it & 1) * 65536 + q * 16384 + c * 256;
#pragma unroll
        for (int r = 0; r < 4; ++r) {
          float z = s[r] + bf2f(xpv[r]);  // D layout: row=kg*4+r, col=ln
          store_short_sc(h1w + (kg * 4 + r) * 16 + ln, (unsigned)f2bf(tanh_fast(z)));
        }
        asm volatile("s_waitcnt vmcnt(0)" ::: "memory");  // data-store ack
        if (lane == 0)
          __hip_atomic_fetch_add(myA, 1, __ATOMIC_RELAXED, __HIP_MEMORY_SCOPE_SYSTEM);
      }
    } else if (w == 1) {
      if (it >= 1) {  // epilogue layer 1 -> h2[it-1]
        f32x4 s = *(const f32x4*)&red[rp][1][0][lane * 4];
        s += *(const f32x4*)&red[rp][1][1][lane * 4];
        s += *(const f32x4*)&red[rp][1][2][lane * 4];
        s += *(const f32x4*)&red[rp][1][3][lane * 4];
        u16* h2w = h2buf + ((it + 1) & 1) * 65536 + q * 16384 + c * 256;
#pragma unroll
        for (int r = 0; r < 4; ++r) {
          float z = s[r] + bias1;
          store_short_sc(h2w + (kg * 4 + r) * 16 + ln, (unsigned)f2bf(tanh_fast(z)));
        }
        asm volatile("s_waitcnt vmcnt(0)" ::: "memory");
      }
      if (lane == 0)  // it=0: h2[-1] prezeroed, publish without data
        __hip_atomic_fetch_add(myB, 1, __ATOMIC_RELAXED, __HIP_MEMORY_SCOPE_SYSTEM);
    }

    if (it < 512) {
      // poll h1[it] ready -> issue H1 loads -> poll h2[it-1] -> issue H2 loads
      // (identical ordering to round-0; pollB's drain overlaps H1 flight)
      const int tgt = 16 * (it + 1);
      poll_cnt(pA, tgt);
      const u16* p1 = hq1 + (it & 1) * 65536;
      load8_sc(p1, p1 + 2048, H1[0], H1[1], H1[2], H1[3], H1[4], H1[5], H1[6], H1[7]);
      poll_cnt(pB, tgt);
      const u16* p2 = hq2 + ((it + 1) & 1) * 65536;
      load8_sc(p2, p2 + 2048, H2[0], H2[1], H2[2], H2[3], H2[4], H2[5], H2[6], H2[7]);
      if (w == 0 && it < 511) {
#pragma unroll
        for (int r = 0; r < 4; ++r)
          xpv[r] = xp0[((long)(m0 + kg * 4 + r) * 512 + (it + 1)) * 1024 + j0 + ln];
      }
      wait_all16(H1[0], H1[1], H1[2], H1[3], H1[4], H1[5], H1[6], H1[7],
                 H2[0], H2[1], H2[2], H2[3], H2[4], H2[5], H2[6], H2[7]);
    }
  }
}

// ---------------- FC head: out[b] = sigmoid(h2[511][b,:] . fc_w + fc_b) ------
// h2[511] lives at parity 1 in the tiled layout.
__global__ __launch_bounds__(256) void fc_kernel(const u16* __restrict__ h2,
                                                 const float* __restrict__ fcw,
                                                 const float* __restrict__ fcb,
                                                 float* __restrict__ out) {
  const int lane = threadIdx.x & 63;
  const int w = threadIdx.x >> 6;
  float wreg[16];
#pragma unroll
  for (int i = 0; i < 16; ++i) wreg[i] = fcw[lane * 16 + i];
  for (int b = w; b < 64; b += 4) {
    const int q = b >> 4, mb = b & 15;
    const u16* hp = h2 + 65536 + q * 16384 + lane * 256 + mb * 16;  // parity 1
    float s = 0.f;
#pragma unroll
    for (int i = 0; i < 16; ++i) s += bf2f(hp[i]) * wreg[i];
#pragma unroll
    for (int off = 32; off > 0; off >>= 1) s += __shfl_down(s, off, 64);
    if (lane == 0) out[b] = 1.0f / (1.0f + __expf(-(s + fcb[0])));
  }
}

extern "C" void kernel_launch(void* const* d_in, const int* in_sizes, int n_in,
                              void* d_out, int out_size, void* d_ws, size_t ws_size,
                              hipStream_t stream) {
  const float* x    = (const float*)d_in[0];
  const float* wih0 = (const float*)d_in[1];
  const float* whh0 = (const float*)d_in[2];
  const float* bih0 = (const float*)d_in[3];
  const float* bhh0 = (const float*)d_in[4];
  const float* wih1 = (const float*)d_in[5];
  const float* whh1 = (const float*)d_in[6];
  const float* bih1 = (const float*)d_in[7];
  const float* bhh1 = (const float*)d_in[8];
  const float* fcw  = (const float*)d_in[9];
  const float* fcb  = (const float*)d_in[10];

  char* ws = (char*)d_ws;
  u16* xb    = (u16*)(ws);                  // 33,554,432 B
  u16* wih0b = (u16*)(ws + 33554432);       //  1,048,576 B
  u16* whh0b = (u16*)(ws + 34603008);       //  2,097,152 B
  u16* wih1b = (u16*)(ws + 36700160);       //  2,097,152 B
  u16* whh1b = (u16*)(ws + 38797312);       //  2,097,152 B
  u16* xp0   = (u16*)(ws + 40894464);       // 67,108,864 B
  u16* h1buf = (u16*)(ws + 108003328);      //    262,144 B (2 parities, tiled)
  u16* h2buf = (u16*)(ws + 108265472);      //    262,144 B (2 parities, tiled)
  int* bar   = (int*)(ws + 108527616);      //     65,536 B (sub-counters A+B)

  prep_kernel<<<1024, 256, 0, stream>>>(x, wih0, whh0, wih1, whh1, xb, wih0b,
                                        whh0b, wih1b, whh1b, h1buf, bar);
  dim3 gg(256, 8);
  gemm_xproj<<<gg, 256, 0, stream>>>(xb, wih0b, bih0, bhh0, xp0);
  rnn_persist<<<256, 256, 0, stream>>>(whh0b, wih1b, whh1b, xp0, bih1, bhh1,
                                       h1buf, h2buf, bar);
  fc_kernel<<<1, 256, 0, stream>>>(h2buf, fcw, fcb, (float*)d_out);
}

// Round 6
// 2892.084 us; speedup vs baseline: 1.0308x; 1.0126x over previous
//
#include <hip/hip_runtime.h>

typedef unsigned short u16;
typedef __attribute__((ext_vector_type(8))) short short8;
typedef __attribute__((ext_vector_type(4))) float f32x4;

#define GLP(p) ((const __attribute__((address_space(1))) void*)(p))
#define LDSP(p) ((__attribute__((address_space(3))) void*)(p))

__device__ inline u16 f2bf(float f) {
  unsigned u = __float_as_uint(f);
  return (u16)((u + 0x7fffu + ((u >> 16) & 1u)) >> 16);
}
__device__ inline float bf2f(u16 h) {
  return __uint_as_float(((unsigned)h) << 16);
}
__device__ inline float tanh_fast(float x) {
  float e = __expf(2.0f * x);
  return 1.0f - 2.0f / (e + 1.0f);
}
__device__ inline unsigned umin_u(unsigned a, unsigned b) { return a < b ? a : b; }

// ---- LLC-direct (coherence point) access: sc0 sc1 bypass L1/L2 --------------
__device__ inline void store_int_sc(int* p, int v) {
  asm volatile("global_store_dword %0, %1, off sc0 sc1" :: "v"(p), "v"(v) : "memory");
}
// narrow 2-dword gathered probe + drain (the spin body; ~1 RT sampling period)
__device__ inline void probe2_sc(const int* pa, const int* pb, int& a, int& b) {
  asm volatile(
      "global_load_dword %0, %2, off sc0 sc1\n\t"
      "global_load_dword %1, %3, off sc0 sc1\n\t"
      "s_waitcnt vmcnt(0)"
      : "=&v"(a), "=&v"(b) : "v"(pa), "v"(pb) : "memory");
}
// issue 8 LLC-direct 16B loads (no wait): d[i] from {plo,phi} + i*1024B
__device__ inline void load8_sc(const u16* plo, const u16* phi,
                                short8& d0, short8& d1, short8& d2, short8& d3,
                                short8& d4, short8& d5, short8& d6, short8& d7) {
  asm volatile(
      "global_load_dwordx4 %0, %8, off sc0 sc1\n\t"
      "global_load_dwordx4 %1, %8, off offset:1024 sc0 sc1\n\t"
      "global_load_dwordx4 %2, %8, off offset:2048 sc0 sc1\n\t"
      "global_load_dwordx4 %3, %8, off offset:3072 sc0 sc1\n\t"
      "global_load_dwordx4 %4, %9, off sc0 sc1\n\t"
      "global_load_dwordx4 %5, %9, off offset:1024 sc0 sc1\n\t"
      "global_load_dwordx4 %6, %9, off offset:2048 sc0 sc1\n\t"
      "global_load_dwordx4 %7, %9, off offset:3072 sc0 sc1\n\t"
      : "=&v"(d0), "=&v"(d1), "=&v"(d2), "=&v"(d3),
        "=&v"(d4), "=&v"(d5), "=&v"(d6), "=&v"(d7)
      : "v"(plo), "v"(phi)
      : "memory");
}
// drain all outstanding vmem; ties the 16 fragment values so uses can't hoist
__device__ inline void wait_all16(short8& a0, short8& a1, short8& a2, short8& a3,
                                  short8& a4, short8& a5, short8& a6, short8& a7,
                                  short8& b0, short8& b1, short8& b2, short8& b3,
                                  short8& b4, short8& b5, short8& b6, short8& b7) {
  asm volatile("s_waitcnt vmcnt(0)"
               : "+v"(a0), "+v"(a1), "+v"(a2), "+v"(a3),
                 "+v"(a4), "+v"(a5), "+v"(a6), "+v"(a7),
                 "+v"(b0), "+v"(b1), "+v"(b2), "+v"(b3),
                 "+v"(b4), "+v"(b5), "+v"(b6), "+v"(b7)
               :: "memory");
}
__device__ inline unsigned min8(const short8& v, unsigned m) {
  unsigned u[4];
  __builtin_memcpy(u, &v, 16);
  m = umin_u(m, u[0]); m = umin_u(m, u[1]);
  m = umin_u(m, u[2]); m = umin_u(m, u[3]);
  return m;
}

// ---------------- prep: fp32 -> bf16 conversions -----------------------------
__device__ inline void convseg(const float* __restrict__ s, u16* __restrict__ d,
                               long n4, long t, long S) {
  for (long i = t; i < n4; i += S) {
    float4 v = ((const float4*)s)[i];
    ushort4 o;
    o.x = f2bf(v.x); o.y = f2bf(v.y); o.z = f2bf(v.z); o.w = f2bf(v.w);
    ((ushort4*)d)[i] = o;
  }
}

__global__ __launch_bounds__(256) void prep_kernel(
    const float* __restrict__ x, const float* __restrict__ wih0,
    const float* __restrict__ whh0, const float* __restrict__ wih1,
    const float* __restrict__ whh1,
    u16* __restrict__ xb, u16* __restrict__ wih0b, u16* __restrict__ whh0b,
    u16* __restrict__ wih1b, u16* __restrict__ whh1b) {
  long t = blockIdx.x * 256L + threadIdx.x;
  long S = (long)gridDim.x * 256L;
  convseg(x,    xb,    16777216 / 4, t, S);
  convseg(wih0, wih0b,   524288 / 4, t, S);
  convseg(whh0, whh0b,  1048576 / 4, t, S);
  convseg(wih1, wih1b,  1048576 / 4, t, S);
  convseg(whh1, whh1b,  1048576 / 4, t, S);
}

// init the 1MB h-ring region (runs AFTER gemm_xproj; overlays dead xb).
// h2 ring slot 3 (bytes [917504,1048576)) is pre-filled with 0x8000 (-0.0):
// numerically zero (initial h2[-1]) but nonzero bits, so the sentinel poll
// accepts it with no special-casing. Everything else zeroed.
__global__ __launch_bounds__(256) void zero_kernel(int4* __restrict__ p) {
  long i = blockIdx.x * 256L + threadIdx.x;
  int fill = (i >= 57344) ? (int)0x80008000 : 0;
  p[i] = make_int4(fill, fill, fill, fill);
}

// ---------------- GEMM: xp0[m][n] = sum_k x[m][k]*Wih0[n][k] + bih0[n]+bhh0[n]
// M=32768, N=1024, K=512; bf16 in, bf16 out (fp32 accum)
__global__ __launch_bounds__(256, 2) void gemm_xproj(
    const u16* __restrict__ A,   // 32768 x 512
    const u16* __restrict__ Bw,  // 1024 x 512
    const float* __restrict__ bi, const float* __restrict__ bh,
    u16* __restrict__ C) {       // 32768 x 1024
  __shared__ u16 As[128 * 64];
  __shared__ u16 Bs[128 * 64];
  const int tid = threadIdx.x;
  const int lane = tid & 63;
  const int w = tid >> 6;
  const int ln = lane & 15, kg = lane >> 4;
  const int m0 = blockIdx.x * 128;
  const int n0 = blockIdx.y * 128;
  const int mi = (w & 1) * 64, ni = (w >> 1) * 64;

  f32x4 acc[4][4] = {};
  float bias[4];
#pragma unroll
  for (int nj = 0; nj < 4; ++nj) bias[nj] = bi[n0 + ni + nj * 16 + ln] + bh[n0 + ni + nj * 16 + ln];

  const int lrow = lane >> 3;
  const int lcol = (lane & 7) * 8;

  for (int kt = 0; kt < 512; kt += 64) {
#pragma unroll
    for (int i = 0; i < 4; ++i) {
      int row = i * 32 + w * 8;
      const u16* ga = A + (long)(m0 + row + lrow) * 512 + kt + lcol;
      __builtin_amdgcn_global_load_lds(GLP(ga), LDSP(As + row * 64), 16, 0, 0);
      const u16* gb = Bw + (long)(n0 + row + lrow) * 512 + kt + lcol;
      __builtin_amdgcn_global_load_lds(GLP(gb), LDSP(Bs + row * 64), 16, 0, 0);
    }
    __syncthreads();
#pragma unroll
    for (int kc = 0; kc < 64; kc += 32) {
      short8 af[4], bf[4];
#pragma unroll
      for (int i = 0; i < 4; ++i) {
        af[i] = *(const short8*)(As + (mi + i * 16 + ln) * 64 + kc + kg * 8);
        bf[i] = *(const short8*)(Bs + (ni + i * 16 + ln) * 64 + kc + kg * 8);
      }
#pragma unroll
      for (int a = 0; a < 4; ++a)
#pragma unroll
        for (int b = 0; b < 4; ++b)
          acc[a][b] = __builtin_amdgcn_mfma_f32_16x16x32_bf16(af[a], bf[b], acc[a][b], 0, 0, 0);
    }
    __syncthreads();
  }
#pragma unroll
  for (int a = 0; a < 4; ++a)
#pragma unroll
    for (int b = 0; b < 4; ++b)
#pragma unroll
      for (int r = 0; r < 4; ++r) {
        int m = m0 + mi + a * 16 + kg * 4 + r;
        int n = n0 + ni + b * 16 + ln;
        C[(long)m * 1024 + n] = f2bf(acc[a][b][r] + bias[b]);
      }
}

// ---------------- persistent pipelined 2-layer recurrence --------------------
// NARROW-PROBE SENTINEL PROTOCOL (r0 geometry, r4 data encoding, new poll).
// 256 blocks x 256 threads; block = (q 0..3) x (c 0..63). 4-slot rings, tiles
// as the verified baseline (tile c = contiguous 512B [16 m][16 j]). Producer:
// dword-paired stores (shfl_xor lane pairing; +0 -> -0 so live data has no
// zero dword) - NO store-ack, NO flag (removes ~1.5 system-scope RTs).
// Consumer: spins on a 2-instruction gathered probe - lane l samples one dword
// of tile (l&15) in both layers, so one probe covers ALL 16 producer tiles
// this wave consumes; 512B/wave/spin (r4's traffic mistake fixed). On probe
// success: bulk-load once, validate all dwords nonzero, rare bounded retry.
// Ring recycling off the critical path: pre-MFMA(it), owner zeroes its tile in
// h1 slot (it+2)&3 (gen it-2) / h2 slot (it+1)&3 (gen it-3). Safe: any block
// at it implies every block completed load(it-2) (validated h1[it-1] requires
// all epilogue(it-1), which requires all load(it-2)); zeroes are vmcnt-drained
// by the owner's wait at load(it), a full iteration before the slot is probed.
// Spin/retry budgets convert any protocol violation into a bounded wrong
// answer instead of a hang.
__global__ __launch_bounds__(256, 1) void rnn_persist(
    const u16* __restrict__ whh0, const u16* __restrict__ wih1,
    const u16* __restrict__ whh1, const u16* __restrict__ xp0,
    const float* __restrict__ bih1, const float* __restrict__ bhh1,
    u16* __restrict__ h1buf, u16* __restrict__ h2buf) {
  const int tid = threadIdx.x;
  const int lane = tid & 63;
  const int w = tid >> 6;
  const int ln = lane & 15, kg = lane >> 4;
  const int q = blockIdx.x >> 6;
  const int c = blockIdx.x & 63;
  const int m0 = q * 16;
  const int j0 = c * 16;
  const int kb = w * 256;  // this wave's K-chunk base (K split 4 ways)

  // persistent weight fragments (B-operand layout: n=lane&15 -> row j0+ln)
  short8 WA[8], W1[8], W2[8];
#pragma unroll
  for (int i = 0; i < 8; ++i) {
    int off = (j0 + ln) * 1024 + kb + i * 32 + kg * 8;
    WA[i] = *(const short8*)(whh0 + off);
    W1[i] = *(const short8*)(wih1 + off);
    W2[i] = *(const short8*)(whh1 + off);
  }
  const float bias1 = bih1[j0 + ln] + bhh1[j0 + ln];

  __shared__ float red[2][2][4][256];  // [it parity][layer][wave][lane*4]

  // consumer A-fragment base (tiled layout), per wave/lane:
  // elem = (w*16 + (kg>>1) + i*2)*256 + ln*16 + (kg&1)*8, i advances by 512
  const int lbase = (w * 16 + (kg >> 1)) * 256 + ln * 16 + (kg & 1) * 8;
  const u16* hq1 = h1buf + q * 16384 + lbase;  // + slot*65536
  const u16* hq2 = h2buf + q * 16384 + lbase;
  // probe base: lane l samples tile (w*16 + (l&15)), dword at row (l>>4)*4
  const int pbase = q * 16384 + (w * 16 + ln) * 256 + kg * 64;

  short8 H1[8], H2[8];
  u16 xpv[4];

  // initial state: h1[-1] = 0, h2[-2] = 0 as plain zero registers
  short8 zz = {0, 0, 0, 0, 0, 0, 0, 0};
#pragma unroll
  for (int i = 0; i < 8; ++i) { H1[i] = zz; H2[i] = zz; }
  if (w == 0) {
#pragma unroll
    for (int r = 0; r < 4; ++r)
      xpv[r] = xp0[((long)(m0 + kg * 4 + r) * 512 + 0) * 1024 + j0 + ln];
  }

  for (int it = 0; it <= 512; ++it) {
    // ---- pre-MFMA ring recycle (off the critical path; see header proof) ---
    if ((ln & 1) == 0) {
      if (w == 0) {
        u16* z = h1buf + ((it + 2) & 3) * 65536 + q * 16384 + c * 256;
#pragma unroll
        for (int r = 0; r < 4; ++r) store_int_sc((int*)(z + (kg * 4 + r) * 16 + ln), 0);
      } else if (w == 1) {
        u16* z = h2buf + ((it + 1) & 3) * 65536 + q * 16384 + c * 256;
#pragma unroll
        for (int r = 0; r < 4; ++r) store_int_sc((int*)(z + (kg * 4 + r) * 16 + ln), 0);
      }
    }

    const int rp = it & 1;
    f32x4 accA = {}, accB = {};
#pragma unroll
    for (int i = 0; i < 8; ++i) accA = __builtin_amdgcn_mfma_f32_16x16x32_bf16(H1[i], WA[i], accA, 0, 0, 0);
#pragma unroll
    for (int i = 0; i < 8; ++i) accB = __builtin_amdgcn_mfma_f32_16x16x32_bf16(H1[i], W1[i], accB, 0, 0, 0);
#pragma unroll
    for (int i = 0; i < 8; ++i) accB = __builtin_amdgcn_mfma_f32_16x16x32_bf16(H2[i], W2[i], accB, 0, 0, 0);
    *(f32x4*)&red[rp][0][w][lane * 4] = accA;
    *(f32x4*)&red[rp][1][w][lane * 4] = accB;
    __syncthreads();  // the ONLY workgroup barrier this iteration

    if (w == 0) {
      if (it < 512) {  // epilogue layer 0 -> h1[it], slot it&3
        f32x4 s = *(const f32x4*)&red[rp][0][0][lane * 4];
        s += *(const f32x4*)&red[rp][0][1][lane * 4];
        s += *(const f32x4*)&red[rp][0][2][lane * 4];
        s += *(const f32x4*)&red[rp][0][3][lane * 4];
        u16* h1w = h1buf + (it & 3) * 65536 + q * 16384 + c * 256;
#pragma unroll
        for (int r = 0; r < 4; ++r) {
          float z = s[r] + bf2f(xpv[r]);  // D layout: row=kg*4+r, col=ln
          unsigned hv = (unsigned)f2bf(tanh_fast(z));
          if (hv == 0u) hv = 0x8000u;  // -0.0: same value, nonzero bits
          unsigned pv = ((unsigned)__shfl_xor((int)hv, 1, 64)) & 0xFFFFu;
          if ((ln & 1) == 0)  // dword-atomic paired store; no ack, no flag
            store_int_sc((int*)(h1w + (kg * 4 + r) * 16 + ln), (int)(hv | (pv << 16)));
        }
      }
    } else if (w == 1) {
      if (it >= 1) {  // epilogue layer 1 -> h2[it-1], slot (it-1)&3
        f32x4 s = *(const f32x4*)&red[rp][1][0][lane * 4];
        s += *(const f32x4*)&red[rp][1][1][lane * 4];
        s += *(const f32x4*)&red[rp][1][2][lane * 4];
        s += *(const f32x4*)&red[rp][1][3][lane * 4];
        u16* h2w = h2buf + ((it - 1) & 3) * 65536 + q * 16384 + c * 256;
#pragma unroll
        for (int r = 0; r < 4; ++r) {
          float z = s[r] + bias1;
          unsigned hv = (unsigned)f2bf(tanh_fast(z));
          if (hv == 0u) hv = 0x8000u;
          unsigned pv = ((unsigned)__shfl_xor((int)hv, 1, 64)) & 0xFFFFu;
          if ((ln & 1) == 0)
            store_int_sc((int*)(h2w + (kg * 4 + r) * 16 + ln), (int)(hv | (pv << 16)));
        }
      }
    }

    if (it < 512) {
      // ---- narrow gathered probe: covers all 16 H1 + 16 H2 tiles this wave
      // consumes; sampling period ~1 RT, 512B/wave/spin --------------------
      const int* qa = (const int*)(h1buf + (it & 3) * 65536 + pbase);
      const int* qb = (const int*)(h2buf + ((it - 1) & 3) * 65536 + pbase);
      int a, b;
      int sbud = 1 << 22;
      do {
        probe2_sc(qa, qb, a, b);
      } while (!__all(a != 0 && b != 0) && --sbud != 0);

      // ---- bulk load (exactly once in steady state) ----------------------
      const u16* p1 = hq1 + (it & 3) * 65536;
      const u16* p2 = hq2 + ((it - 1) & 3) * 65536;
      load8_sc(p1, p1 + 2048, H1[0], H1[1], H1[2], H1[3], H1[4], H1[5], H1[6], H1[7]);
      load8_sc(p2, p2 + 2048, H2[0], H2[1], H2[2], H2[3], H2[4], H2[5], H2[6], H2[7]);
      if (w == 0 && it < 511) {
#pragma unroll
        for (int r = 0; r < 4; ++r)
          xpv[r] = xp0[((long)(m0 + kg * 4 + r) * 512 + (it + 1)) * 1024 + j0 + ln];
      }
      wait_all16(H1[0], H1[1], H1[2], H1[3], H1[4], H1[5], H1[6], H1[7],
                 H2[0], H2[1], H2[2], H2[3], H2[4], H2[5], H2[6], H2[7]);

      // ---- validate; rare bounded retry (probe certified all producers
      // were mid-epilogue, so lagging dwords are ~100s of cycles behind) ----
      int rbud = 1 << 16;
      while (true) {
        unsigned mm = 0xFFFFFFFFu;
#pragma unroll
        for (int i = 0; i < 8; ++i) mm = min8(H1[i], mm);
#pragma unroll
        for (int i = 0; i < 8; ++i) mm = min8(H2[i], mm);
        if (__all(mm != 0u) || --rbud == 0) break;
        load8_sc(p1, p1 + 2048, H1[0], H1[1], H1[2], H1[3], H1[4], H1[5], H1[6], H1[7]);
        load8_sc(p2, p2 + 2048, H2[0], H2[1], H2[2], H2[3], H2[4], H2[5], H2[6], H2[7]);
        wait_all16(H1[0], H1[1], H1[2], H1[3], H1[4], H1[5], H1[6], H1[7],
                   H2[0], H2[1], H2[2], H2[3], H2[4], H2[5], H2[6], H2[7]);
      }
    }
  }
}

// ---------------- FC head: out[b] = sigmoid(h2[511][b,:] . fc_w + fc_b) ------
// h2[511] lives in ring slot 511&3 = 3 (tiled layout).
__global__ __launch_bounds__(256) void fc_kernel(const u16* __restrict__ h2,
                                                 const float* __restrict__ fcw,
                                                 const float* __restrict__ fcb,
                                                 float* __restrict__ out) {
  const int lane = threadIdx.x & 63;
  const int w = threadIdx.x >> 6;
  float wreg[16];
#pragma unroll
  for (int i = 0; i < 16; ++i) wreg[i] = fcw[lane * 16 + i];
  for (int b = w; b < 64; b += 4) {
    const int q = b >> 4, mb = b & 15;
    const u16* hp = h2 + 3 * 65536 + q * 16384 + lane * 256 + mb * 16;  // slot 3
    float s = 0.f;
#pragma unroll
    for (int i = 0; i < 16; ++i) s += bf2f(hp[i]) * wreg[i];
#pragma unroll
    for (int off = 32; off > 0; off >>= 1) s += __shfl_down(s, off, 64);
    if (lane == 0) out[b] = 1.0f / (1.0f + __expf(-(s + fcb[0])));
  }
}

extern "C" void kernel_launch(void* const* d_in, const int* in_sizes, int n_in,
                              void* d_out, int out_size, void* d_ws, size_t ws_size,
                              hipStream_t stream) {
  const float* x    = (const float*)d_in[0];
  const float* wih0 = (const float*)d_in[1];
  const float* whh0 = (const float*)d_in[2];
  const float* bih0 = (const float*)d_in[3];
  const float* bhh0 = (const float*)d_in[4];
  const float* wih1 = (const float*)d_in[5];
  const float* whh1 = (const float*)d_in[6];
  const float* bih1 = (const float*)d_in[7];
  const float* bhh1 = (const float*)d_in[8];
  const float* fcw  = (const float*)d_in[9];
  const float* fcb  = (const float*)d_in[10];

  char* ws = (char*)d_ws;
  u16* xb    = (u16*)(ws);                  // 33,554,432 B (dead after gemm)
  u16* h1buf = (u16*)(ws);                  //    524,288 B (4 slots) overlays xb
  u16* h2buf = (u16*)(ws + 524288);         //    524,288 B (4 slots) overlays xb
  u16* wih0b = (u16*)(ws + 33554432);       //  1,048,576 B
  u16* whh0b = (u16*)(ws + 34603008);       //  2,097,152 B
  u16* wih1b = (u16*)(ws + 36700160);       //  2,097,152 B
  u16* whh1b = (u16*)(ws + 38797312);       //  2,097,152 B
  u16* xp0   = (u16*)(ws + 40894464);       // 67,108,864 B

  prep_kernel<<<1024, 256, 0, stream>>>(x, wih0, whh0, wih1, whh1, xb, wih0b,
                                        whh0b, wih1b, whh1b);
  dim3 gg(256, 8);
  gemm_xproj<<<gg, 256, 0, stream>>>(xb, wih0b, bih0, bhh0, xp0);
  zero_kernel<<<256, 256, 0, stream>>>((int4*)ws);  // init h rings (1MB)
  rnn_persist<<<256, 256, 0, stream>>>(whh0b, wih1b, whh1b, xp0, bih1, bhh1,
                                       h1buf, h2buf);
  fc_kernel<<<1, 256, 0, stream>>>(h2buf, fcw, fcb, (float*)d_out);
}

// Round 7
// 1683.699 us; speedup vs baseline: 1.7707x; 1.7177x over previous
//
#include <hip/hip_runtime.h>

typedef unsigned short u16;
typedef __attribute__((ext_vector_type(8))) short short8;
typedef __attribute__((ext_vector_type(4))) float f32x4;

#define GLP(p) ((const __attribute__((address_space(1))) void*)(p))
#define LDSP(p) ((__attribute__((address_space(3))) void*)(p))

__device__ inline u16 f2bf(float f) {
  unsigned u = __float_as_uint(f);
  return (u16)((u + 0x7fffu + ((u >> 16) & 1u)) >> 16);
}
__device__ inline float bf2f(u16 h) {
  return __uint_as_float(((unsigned)h) << 16);
}
__device__ inline float tanh_fast(float x) {
  float e = __expf(2.0f * x);
  return 1.0f - 2.0f / (e + 1.0f);
}

// ---- LLC-direct (coherence point) access helpers: sc0 sc1 bypass L1/L2 ------
__device__ inline void store_short_sc(u16* p, unsigned v) {
  asm volatile("global_store_short %0, %1, off sc0 sc1" :: "v"(p), "v"(v) : "memory");
}
__device__ inline void store_int_sc(int* p, int v) {
  asm volatile("global_store_dword %0, %1, off sc0 sc1" :: "v"(p), "v"(v) : "memory");
}
__device__ inline int load_int_sc(const int* p) {
  int v;
  asm volatile("global_load_dword %0, %1, off sc0 sc1\n\t"
               "s_waitcnt vmcnt(0)"
               : "=&v"(v) : "v"(p) : "memory");
  return v;
}
// issue 8 LLC-direct 16B loads (no wait): d[i] from {plo,phi} + i*1024B
__device__ inline void load8_sc(const u16* plo, const u16* phi,
                                short8& d0, short8& d1, short8& d2, short8& d3,
                                short8& d4, short8& d5, short8& d6, short8& d7) {
  asm volatile(
      "global_load_dwordx4 %0, %8, off sc0 sc1\n\t"
      "global_load_dwordx4 %1, %8, off offset:1024 sc0 sc1\n\t"
      "global_load_dwordx4 %2, %8, off offset:2048 sc0 sc1\n\t"
      "global_load_dwordx4 %3, %8, off offset:3072 sc0 sc1\n\t"
      "global_load_dwordx4 %4, %9, off sc0 sc1\n\t"
      "global_load_dwordx4 %5, %9, off offset:1024 sc0 sc1\n\t"
      "global_load_dwordx4 %6, %9, off offset:2048 sc0 sc1\n\t"
      "global_load_dwordx4 %7, %9, off offset:3072 sc0 sc1\n\t"
      : "=&v"(d0), "=&v"(d1), "=&v"(d2), "=&v"(d3),
        "=&v"(d4), "=&v"(d5), "=&v"(d6), "=&v"(d7)
      : "v"(plo), "v"(phi)
      : "memory");
}
// drain all outstanding vmem; ties the 16 fragment values so MFMAs can't hoist
__device__ inline void wait_all16(short8& a0, short8& a1, short8& a2, short8& a3,
                                  short8& a4, short8& a5, short8& a6, short8& a7,
                                  short8& b0, short8& b1, short8& b2, short8& b3,
                                  short8& b4, short8& b5, short8& b6, short8& b7) {
  asm volatile("s_waitcnt vmcnt(0)"
               : "+v"(a0), "+v"(a1), "+v"(a2), "+v"(a3),
                 "+v"(a4), "+v"(a5), "+v"(a6), "+v"(a7),
                 "+v"(b0), "+v"(b1), "+v"(b2), "+v"(b3),
                 "+v"(b4), "+v"(b5), "+v"(b6), "+v"(b7)
               :: "memory");
}
// poll 64 per-producer flags (128B stride) until all >= target (r0-verified)
__device__ inline void poll_flags(const int* fbase, int lane, int target) {
  const int* fp = fbase + lane * 32;
  while (load_int_sc(fp) < target) {}
}

// ---------------- prep: fp32 -> bf16 conversions, zero h buffers & flags -----
__device__ inline void convseg(const float* __restrict__ s, u16* __restrict__ d,
                               long n4, long t, long S) {
  for (long i = t; i < n4; i += S) {
    float4 v = ((const float4*)s)[i];
    ushort4 o;
    o.x = f2bf(v.x); o.y = f2bf(v.y); o.z = f2bf(v.z); o.w = f2bf(v.w);
    ((ushort4*)d)[i] = o;
  }
}

__global__ __launch_bounds__(256) void prep_kernel(
    const float* __restrict__ x, const float* __restrict__ wih0,
    const float* __restrict__ whh0, const float* __restrict__ wih1,
    const float* __restrict__ whh1,
    u16* __restrict__ xb, u16* __restrict__ wih0b, u16* __restrict__ whh0b,
    u16* __restrict__ wih1b, u16* __restrict__ whh1b,
    u16* __restrict__ hbufs, int* __restrict__ bar) {
  long t = blockIdx.x * 256L + threadIdx.x;
  long S = (long)gridDim.x * 256L;
  convseg(x,    xb,    16777216 / 4, t, S);
  convseg(wih0, wih0b,   524288 / 4, t, S);
  convseg(whh0, whh0b,  1048576 / 4, t, S);
  convseg(wih1, wih1b,  1048576 / 4, t, S);
  convseg(whh1, whh1b,  1048576 / 4, t, S);
  // zero h1(2 parities) + h2(2 parities): 524288 B = 65536 ushort4
  ushort4 z4 = make_ushort4(0, 0, 0, 0);
  for (long i = t; i < 65536; i += S) ((ushort4*)hbufs)[i] = z4;
  // zero flag region: 16384 ints = 4096 int4
  int4 zi = make_int4(0, 0, 0, 0);
  for (long i = t; i < 4096; i += S) ((int4*)bar)[i] = zi;
}

// ---------------- GEMM: xp0[m][n] = sum_k x[m][k]*Wih0[n][k] + bih0[n]+bhh0[n]
// M=32768, N=1024, K=512; bf16 in, bf16 out (fp32 accum)
__global__ __launch_bounds__(256, 2) void gemm_xproj(
    const u16* __restrict__ A,   // 32768 x 512
    const u16* __restrict__ Bw,  // 1024 x 512
    const float* __restrict__ bi, const float* __restrict__ bh,
    u16* __restrict__ C) {       // 32768 x 1024
  __shared__ u16 As[128 * 64];
  __shared__ u16 Bs[128 * 64];
  const int tid = threadIdx.x;
  const int lane = tid & 63;
  const int w = tid >> 6;
  const int ln = lane & 15, kg = lane >> 4;
  const int m0 = blockIdx.x * 128;
  const int n0 = blockIdx.y * 128;
  const int mi = (w & 1) * 64, ni = (w >> 1) * 64;

  f32x4 acc[4][4] = {};
  float bias[4];
#pragma unroll
  for (int nj = 0; nj < 4; ++nj) bias[nj] = bi[n0 + ni + nj * 16 + ln] + bh[n0 + ni + nj * 16 + ln];

  const int lrow = lane >> 3;
  const int lcol = (lane & 7) * 8;

  for (int kt = 0; kt < 512; kt += 64) {
#pragma unroll
    for (int i = 0; i < 4; ++i) {
      int row = i * 32 + w * 8;
      const u16* ga = A + (long)(m0 + row + lrow) * 512 + kt + lcol;
      __builtin_amdgcn_global_load_lds(GLP(ga), LDSP(As + row * 64), 16, 0, 0);
      const u16* gb = Bw + (long)(n0 + row + lrow) * 512 + kt + lcol;
      __builtin_amdgcn_global_load_lds(GLP(gb), LDSP(Bs + row * 64), 16, 0, 0);
    }
    __syncthreads();
#pragma unroll
    for (int kc = 0; kc < 64; kc += 32) {
      short8 af[4], bf[4];
#pragma unroll
      for (int i = 0; i < 4; ++i) {
        af[i] = *(const short8*)(As + (mi + i * 16 + ln) * 64 + kc + kg * 8);
        bf[i] = *(const short8*)(Bs + (ni + i * 16 + ln) * 64 + kc + kg * 8);
      }
#pragma unroll
      for (int a = 0; a < 4; ++a)
#pragma unroll
        for (int b = 0; b < 4; ++b)
          acc[a][b] = __builtin_amdgcn_mfma_f32_16x16x32_bf16(af[a], bf[b], acc[a][b], 0, 0, 0);
    }
    __syncthreads();
  }
#pragma unroll
  for (int a = 0; a < 4; ++a)
#pragma unroll
    for (int b = 0; b < 4; ++b)
#pragma unroll
      for (int r = 0; r < 4; ++r) {
        int m = m0 + mi + a * 16 + kg * 4 + r;
        int n = n0 + ni + b * 16 + ln;
        C[(long)m * 1024 + n] = f2bf(acc[a][b][r] + bias[b]);
      }
}

// ---------------- persistent pipelined 2-layer recurrence --------------------
// 256 blocks x 256 threads; block = (q in 0..3) x (c in 0..63); group = 64
// blocks sharing q. Tile-blocked h bufs, parity double-buffer, exactly as the
// verified 1977us baseline. SINGLE-HANDSHAKE change vs r0: the two flags
// (A: h1 ready, B: h2 ready) are merged into ONE flag published after BOTH
// epilogue waves have vmcnt(0)-ack'd their data stores (ordered by a second
// __syncthreads). Consumer: ONE poll -> issue all 16 H1+H2 loads -> one drain.
// This removes the serialized pollB leg, whose first probe drained the
// in-flight H1 loads (~1 extra RT/iter in r0). xp0 prefetch stays AFTER the
// poll (r3 lesson: anything in the vmem queue when a poll's vmcnt(0) runs is
// drained on the critical path).
__global__ __launch_bounds__(256, 1) void rnn_persist(
    const u16* __restrict__ whh0, const u16* __restrict__ wih1,
    const u16* __restrict__ whh1, const u16* __restrict__ xp0,
    const float* __restrict__ bih1, const float* __restrict__ bhh1,
    u16* __restrict__ h1buf, u16* __restrict__ h2buf, int* __restrict__ bar) {
  const int tid = threadIdx.x;
  const int lane = tid & 63;
  const int w = tid >> 6;
  const int ln = lane & 15, kg = lane >> 4;
  const int q = blockIdx.x >> 6;
  const int c = blockIdx.x & 63;
  const int m0 = q * 16;
  const int j0 = c * 16;
  const int kb = w * 256;  // this wave's K-chunk base (K split 4 ways)

  // persistent weight fragments (B-operand layout: n=lane&15 -> row j0+ln)
  short8 WA[8], W1[8], W2[8];
#pragma unroll
  for (int i = 0; i < 8; ++i) {
    int off = (j0 + ln) * 1024 + kb + i * 32 + kg * 8;
    WA[i] = *(const short8*)(whh0 + off);
    W1[i] = *(const short8*)(wih1 + off);
    W2[i] = *(const short8*)(whh1 + off);
  }
  const float bias1 = bih1[j0 + ln] + bhh1[j0 + ln];

  __shared__ float red[2][2][4][256];  // [it parity][layer][wave][lane*4]
  int* flags = bar + q * 64 * 32;      // ONE flag per producer, 128B stride
  int* myF = flags + c * 32;

  // consumer A-fragment base (tiled layout), per wave/lane:
  // elem = (w*16 + (kg>>1) + i*2)*256 + ln*16 + (kg&1)*8, i advances by 512
  const int lbase = (w * 16 + (kg >> 1)) * 256 + ln * 16 + (kg & 1) * 8;
  const u16* hq1 = h1buf + q * 16384 + lbase;  // + parity*65536
  const u16* hq2 = h2buf + q * 16384 + lbase;

  short8 H1[8], H2[8];
  u16 xpv[4];

  // ---- initial state: h1[-1] = 0, h2[-2] = 0 (prep zeroed the buffers;
  // register zero-init is numerically identical and saves the startup RT) ----
  short8 zz = {0, 0, 0, 0, 0, 0, 0, 0};
#pragma unroll
  for (int i = 0; i < 8; ++i) { H1[i] = zz; H2[i] = zz; }
  if (w == 0) {
#pragma unroll
    for (int r = 0; r < 4; ++r)
      xpv[r] = xp0[((long)(m0 + kg * 4 + r) * 512 + 0) * 1024 + j0 + ln];
  }

  for (int it = 0; it <= 512; ++it) {
    const int rp = it & 1;
    f32x4 accA = {}, accB = {};
#pragma unroll
    for (int i = 0; i < 8; ++i) accA = __builtin_amdgcn_mfma_f32_16x16x32_bf16(H1[i], WA[i], accA, 0, 0, 0);
#pragma unroll
    for (int i = 0; i < 8; ++i) accB = __builtin_amdgcn_mfma_f32_16x16x32_bf16(H1[i], W1[i], accB, 0, 0, 0);
#pragma unroll
    for (int i = 0; i < 8; ++i) accB = __builtin_amdgcn_mfma_f32_16x16x32_bf16(H2[i], W2[i], accB, 0, 0, 0);
    *(f32x4*)&red[rp][0][w][lane * 4] = accA;
    *(f32x4*)&red[rp][1][w][lane * 4] = accB;
    __syncthreads();  // barrier 1: red[rp] complete

    if (w == 0) {
      if (it < 512) {  // epilogue layer 0 -> h1[it] (tile-blocked, exclusive)
        f32x4 s = *(const f32x4*)&red[rp][0][0][lane * 4];
        s += *(const f32x4*)&red[rp][0][1][lane * 4];
        s += *(const f32x4*)&red[rp][0][2][lane * 4];
        s += *(const f32x4*)&red[rp][0][3][lane * 4];
        u16* h1w = h1buf + (it & 1) * 65536 + q * 16384 + c * 256;
#pragma unroll
        for (int r = 0; r < 4; ++r) {
          float z = s[r] + bf2f(xpv[r]);  // D layout: row=kg*4+r, col=ln
          store_short_sc(h1w + (kg * 4 + r) * 16 + ln, (unsigned)f2bf(tanh_fast(z)));
        }
        asm volatile("s_waitcnt vmcnt(0)" ::: "memory");  // h1 stores visible
      }
    } else if (w == 1) {
      if (it >= 1) {  // epilogue layer 1 -> h2[it-1]
        f32x4 s = *(const f32x4*)&red[rp][1][0][lane * 4];
        s += *(const f32x4*)&red[rp][1][1][lane * 4];
        s += *(const f32x4*)&red[rp][1][2][lane * 4];
        s += *(const f32x4*)&red[rp][1][3][lane * 4];
        u16* h2w = h2buf + ((it + 1) & 1) * 65536 + q * 16384 + c * 256;
#pragma unroll
        for (int r = 0; r < 4; ++r) {
          float z = s[r] + bias1;
          store_short_sc(h2w + (kg * 4 + r) * 16 + ln, (unsigned)f2bf(tanh_fast(z)));
        }
        asm volatile("s_waitcnt vmcnt(0)" ::: "memory");  // h2 stores visible
      }
    }
    __syncthreads();  // barrier 2: both waves' data acks complete
    if (tid == 0) store_int_sc(myF, it + 1);  // ONE combined publication

    if (it < 512) {
      // ONE poll (both tiles proven visible) -> all 16 loads -> one drain
      poll_flags(flags, lane, it + 1);
      const u16* p1 = hq1 + (it & 1) * 65536;
      load8_sc(p1, p1 + 2048, H1[0], H1[1], H1[2], H1[3], H1[4], H1[5], H1[6], H1[7]);
      const u16* p2 = hq2 + ((it + 1) & 1) * 65536;
      load8_sc(p2, p2 + 2048, H2[0], H2[1], H2[2], H2[3], H2[4], H2[5], H2[6], H2[7]);
      if (w == 0 && it < 511) {
#pragma unroll
        for (int r = 0; r < 4; ++r)
          xpv[r] = xp0[((long)(m0 + kg * 4 + r) * 512 + (it + 1)) * 1024 + j0 + ln];
      }
      wait_all16(H1[0], H1[1], H1[2], H1[3], H1[4], H1[5], H1[6], H1[7],
                 H2[0], H2[1], H2[2], H2[3], H2[4], H2[5], H2[6], H2[7]);
    }
  }
}

// ---------------- FC head: out[b] = sigmoid(h2[511][b,:] . fc_w + fc_b) ------
// h2[511] lives at parity 1 in the tiled layout.
__global__ __launch_bounds__(256) void fc_kernel(const u16* __restrict__ h2,
                                                 const float* __restrict__ fcw,
                                                 const float* __restrict__ fcb,
                                                 float* __restrict__ out) {
  const int lane = threadIdx.x & 63;
  const int w = threadIdx.x >> 6;
  float wreg[16];
#pragma unroll
  for (int i = 0; i < 16; ++i) wreg[i] = fcw[lane * 16 + i];
  for (int b = w; b < 64; b += 4) {
    const int q = b >> 4, mb = b & 15;
    const u16* hp = h2 + 65536 + q * 16384 + lane * 256 + mb * 16;  // parity 1
    float s = 0.f;
#pragma unroll
    for (int i = 0; i < 16; ++i) s += bf2f(hp[i]) * wreg[i];
#pragma unroll
    for (int off = 32; off > 0; off >>= 1) s += __shfl_down(s, off, 64);
    if (lane == 0) out[b] = 1.0f / (1.0f + __expf(-(s + fcb[0])));
  }
}

extern "C" void kernel_launch(void* const* d_in, const int* in_sizes, int n_in,
                              void* d_out, int out_size, void* d_ws, size_t ws_size,
                              hipStream_t stream) {
  const float* x    = (const float*)d_in[0];
  const float* wih0 = (const float*)d_in[1];
  const float* whh0 = (const float*)d_in[2];
  const float* bih0 = (const float*)d_in[3];
  const float* bhh0 = (const float*)d_in[4];
  const float* wih1 = (const float*)d_in[5];
  const float* whh1 = (const float*)d_in[6];
  const float* bih1 = (const float*)d_in[7];
  const float* bhh1 = (const float*)d_in[8];
  const float* fcw  = (const float*)d_in[9];
  const float* fcb  = (const float*)d_in[10];

  char* ws = (char*)d_ws;
  u16* xb    = (u16*)(ws);                  // 33,554,432 B
  u16* wih0b = (u16*)(ws + 33554432);       //  1,048,576 B
  u16* whh0b = (u16*)(ws + 34603008);       //  2,097,152 B
  u16* wih1b = (u16*)(ws + 36700160);       //  2,097,152 B
  u16* whh1b = (u16*)(ws + 38797312);       //  2,097,152 B
  u16* xp0   = (u16*)(ws + 40894464);       // 67,108,864 B
  u16* h1buf = (u16*)(ws + 108003328);      //    262,144 B (2 parities, tiled)
  u16* h2buf = (u16*)(ws + 108265472);      //    262,144 B (2 parities, tiled)
  int* bar   = (int*)(ws + 108527616);      //     65,536 B (combined flags)

  prep_kernel<<<1024, 256, 0, stream>>>(x, wih0, whh0, wih1, whh1, xb, wih0b,
                                        whh0b, wih1b, whh1b, h1buf, bar);
  dim3 gg(256, 8);
  gemm_xproj<<<gg, 256, 0, stream>>>(xb, wih0b, bih0, bhh0, xp0);
  rnn_persist<<<256, 256, 0, stream>>>(whh0b, wih1b, whh1b, xp0, bih1, bhh1,
                                       h1buf, h2buf, bar);
  fc_kernel<<<1, 256, 0, stream>>>(h2buf, fcw, fcb, (float*)d_out);
}